// Round 1
// baseline (381.443 us; speedup 1.0000x reference)
//
#include <hip/hip_runtime.h>

#define NROWS 8192      // 4096 x-rows + 4096 y-rows
#define NX    4096
#define D0    2500      // A*B = 100*25
#define LDZ   2560      // K padded to multiple of 64 (and 128)

typedef __attribute__((ext_vector_type(8))) short bf16x8;
typedef __attribute__((ext_vector_type(4))) float f32x4;

typedef __attribute__((address_space(3))) unsigned short lds_ushort_t;
typedef __attribute__((address_space(1))) const unsigned short gbl_ushort_t;

// ---------------------------------------------------------------------------
// Kernel 1: f32 -> bf16 convert (RNE), pad K 2500->2560 with zeros, row norms.
// One block per row, 256 threads. 625 float4 chunks per row.
// ---------------------------------------------------------------------------
__global__ __launch_bounds__(256) void convert_rows(
    const float* __restrict__ x, const float* __restrict__ y,
    unsigned short* __restrict__ Z, float* __restrict__ norms)
{
    int row = blockIdx.x;
    const float* src = (row < NX) ? (x + (size_t)row * D0)
                                  : (y + (size_t)(row - NX) * D0);
    unsigned short* dst = Z + (size_t)row * LDZ;
    int t = threadIdx.x;
    float nrm = 0.f;
    for (int c = t; c < 625; c += 256) {
        float4 v = ((const float4*)src)[c];      // row base byte offset row*10000 is 16B aligned
        float vf[4] = {v.x, v.y, v.z, v.w};
        unsigned short ob[4];
#pragma unroll
        for (int q = 0; q < 4; ++q) {
            unsigned int bits = __float_as_uint(vf[q]);
            unsigned int r16  = (bits + 0x7FFFu + ((bits >> 16) & 1u)) >> 16;  // RNE bf16
            ob[q] = (unsigned short)r16;
            float back = __uint_as_float(((unsigned int)ob[q]) << 16);
            nrm += back * back;                   // norm of the bf16-rounded row
        }
        ushort4 o; o.x = ob[0]; o.y = ob[1]; o.z = ob[2]; o.w = ob[3];
        ((ushort4*)dst)[c] = o;                   // 8B aligned
    }
    if (t < 15) {                                 // zero-pad elements [2500, 2560)
        ushort4 zz; zz.x = zz.y = zz.z = zz.w = 0;
        ((ushort4*)dst)[625 + t] = zz;
    }
    // block reduce the norm
#pragma unroll
    for (int off = 32; off; off >>= 1) nrm += __shfl_down(nrm, off);
    __shared__ float red[4];
    int wave = t >> 6;
    if ((t & 63) == 0) red[wave] = nrm;
    __syncthreads();
    if (t == 0) norms[row] = red[0] + red[1] + red[2] + red[3];
}

// ---------------------------------------------------------------------------
// Kernel 2: fused symmetric Gram + exp + reduce.
// C = Z·Z^T, lower triangle of 64x64 grid of 128x128 tiles.
// m97 structure: BK=64, 4 waves (2x2), 4x4 frags of mfma_f32_16x16x32_bf16,
// global_load_lds width 16, linear LDS, 2 barriers per K-step.
// Epilogue: d2 = n_i + n_j - 2 C_ij ; s = (i==j) ? 1 : exp(-d2/2);
// weight = (diag block ? 1 : 2) * (quadrant sign); one atomicAdd per block.
// ---------------------------------------------------------------------------
__global__ __launch_bounds__(256) void gram_exp_reduce(
    const unsigned short* __restrict__ Z, const float* __restrict__ norms,
    float* __restrict__ accum)
{
    int bi = blockIdx.y, bj = blockIdx.x;
    if (bj > bi) return;                          // lower triangle only

    __shared__ unsigned short As[128 * 64];
    __shared__ unsigned short Bs[128 * 64];
    __shared__ float red[4];

    int tid  = threadIdx.x;
    int wave = tid >> 6, lane = tid & 63;
    int wr = wave >> 1, wc = wave & 1;            // 2x2 wave grid, 64x64 per wave

    const int rowA0 = bi * 128, rowB0 = bj * 128;
    const int lrow8 = lane >> 3;                  // row within 8-row stripe
    const int scol  = (lane & 7) * 8;             // k element offset (8 bf16 = 16B)

    f32x4 zero = {0.f, 0.f, 0.f, 0.f};
    f32x4 acc[4][4];
#pragma unroll
    for (int m = 0; m < 4; ++m)
#pragma unroll
        for (int n = 0; n < 4; ++n) acc[m][n] = zero;

    for (int k0 = 0; k0 < LDZ; k0 += 64) {
        // ---- stage: each wave fills 4 8-row stripes of A and of B ----
#pragma unroll
        for (int q = 0; q < 4; ++q) {
            int rs = wave * 32 + q * 8;           // stripe base row in tile
            int r  = rs + lrow8;
            const unsigned short* ga = Z + (size_t)(rowA0 + r) * LDZ + k0 + scol;
            const unsigned short* gb = Z + (size_t)(rowB0 + r) * LDZ + k0 + scol;
            __builtin_amdgcn_global_load_lds((gbl_ushort_t*)ga,
                (lds_ushort_t*)(As + rs * 64), 16, 0, 0);
            __builtin_amdgcn_global_load_lds((gbl_ushort_t*)gb,
                (lds_ushort_t*)(Bs + rs * 64), 16, 0, 0);
        }
        __syncthreads();                          // compiler drains vmcnt

        // ---- compute: 2 k-slices x 4x4 MFMA ----
#pragma unroll
        for (int ks = 0; ks < 2; ++ks) {
            bf16x8 a[4], b[4];
            int koff = ks * 32 + (lane >> 4) * 8;
#pragma unroll
            for (int m = 0; m < 4; ++m)
                a[m] = *(const bf16x8*)&As[(wr * 64 + m * 16 + (lane & 15)) * 64 + koff];
#pragma unroll
            for (int n = 0; n < 4; ++n)
                b[n] = *(const bf16x8*)&Bs[(wc * 64 + n * 16 + (lane & 15)) * 64 + koff];
#pragma unroll
            for (int m = 0; m < 4; ++m)
#pragma unroll
                for (int n = 0; n < 4; ++n)
                    acc[m][n] = __builtin_amdgcn_mfma_f32_16x16x32_bf16(
                        a[m], b[n], acc[m][n], 0, 0, 0);
        }
        __syncthreads();
    }

    // ---- epilogue ----
    float partial = 0.f;
    int ibl = rowA0 + wr * 64, jbl = rowB0 + wc * 64;
    int r0 = (lane >> 4) * 4, c0 = lane & 15;     // C/D layout: col=lane&15, row=(lane>>4)*4+r
#pragma unroll
    for (int m = 0; m < 4; ++m) {
        int ibase = ibl + m * 16 + r0;
        float ni[4];
#pragma unroll
        for (int r = 0; r < 4; ++r) ni[r] = norms[ibase + r];
#pragma unroll
        for (int n = 0; n < 4; ++n) {
            int j = jbl + n * 16 + c0;
            float nj = norms[j];
#pragma unroll
            for (int r = 0; r < 4; ++r) {
                int i = ibase + r;
                float d2 = ni[r] + nj - 2.f * acc[m][n][r];
                float s = (i == j) ? 1.f : __expf(-0.5f * fmaxf(d2, 0.f));
                partial += s;
            }
        }
    }
    float w = (bi == bj) ? 1.f : 2.f;             // off-diag blocks count (i,j) and (j,i)
    if ((bi < 32) != (bj < 32)) w = -w;           // mixed x/y quadrant -> minus (gives -2*xy)
    partial *= w;

#pragma unroll
    for (int off = 32; off; off >>= 1) partial += __shfl_down(partial, off);
    if ((tid & 63) == 0) red[wave] = partial;
    __syncthreads();
    if (tid == 0) atomicAdd(accum, red[0] + red[1] + red[2] + red[3]);
}

// ---------------------------------------------------------------------------
// Kernel 3: finalize. result = accum / N^2 + (max(1, avg_step) - 1) * 0.002
// ---------------------------------------------------------------------------
__global__ void finalize(const float* __restrict__ accum,
                         const float* __restrict__ avg_step,
                         float* __restrict__ out)
{
    float pen = (fmaxf(1.f, avg_step[0]) - 1.f) * 0.002f;
    out[0] = accum[0] * (1.f / (4096.f * 4096.f)) + pen;
}

extern "C" void kernel_launch(void* const* d_in, const int* in_sizes, int n_in,
                              void* d_out, int out_size, void* d_ws, size_t ws_size,
                              hipStream_t stream) {
    const float* x        = (const float*)d_in[0];
    const float* y        = (const float*)d_in[1];
    const float* avg_step = (const float*)d_in[2];
    float* out = (float*)d_out;

    unsigned short* Z = (unsigned short*)d_ws;
    size_t zbytes = (size_t)NROWS * LDZ * sizeof(unsigned short);   // ~41.9 MB
    float* norms = (float*)((char*)d_ws + zbytes);
    float* accum = norms + NROWS;

    hipMemsetAsync(accum, 0, sizeof(float), stream);
    convert_rows<<<NROWS, 256, 0, stream>>>(x, y, Z, norms);
    dim3 grid(64, 64);
    gram_exp_reduce<<<grid, 256, 0, stream>>>(Z, norms, accum);
    finalize<<<1, 1, 0, stream>>>(accum, avg_step, out);
}

// Round 2
// 226.248 us; speedup vs baseline: 1.6859x; 1.6859x over previous
//
#include <hip/hip_runtime.h>

#define NROWS 8192      // 4096 x-rows + 4096 y-rows
#define NX    4096
#define D0    2500      // A*B = 100*25
#define LDZ   2560      // K padded to multiple of 64 (and 128)
#define NTRI  2080      // 64*65/2 lower-triangle 128x128 tiles
#define NXCD  8

typedef __attribute__((ext_vector_type(8))) short bf16x8;
typedef __attribute__((ext_vector_type(4))) float f32x4;

typedef __attribute__((address_space(3))) unsigned short lds_ushort_t;
typedef __attribute__((address_space(1))) const unsigned short gbl_ushort_t;

// ---------------------------------------------------------------------------
// Kernel 1: f32 -> bf16 convert (RNE), pad K 2500->2560 with zeros, row norms.
// ---------------------------------------------------------------------------
__global__ __launch_bounds__(256) void convert_rows(
    const float* __restrict__ x, const float* __restrict__ y,
    unsigned short* __restrict__ Z, float* __restrict__ norms)
{
    int row = blockIdx.x;
    const float* src = (row < NX) ? (x + (size_t)row * D0)
                                  : (y + (size_t)(row - NX) * D0);
    unsigned short* dst = Z + (size_t)row * LDZ;
    int t = threadIdx.x;
    float nrm = 0.f;
    for (int c = t; c < 625; c += 256) {
        float4 v = ((const float4*)src)[c];
        float vf[4] = {v.x, v.y, v.z, v.w};
        unsigned short ob[4];
#pragma unroll
        for (int q = 0; q < 4; ++q) {
            unsigned int bits = __float_as_uint(vf[q]);
            unsigned int r16  = (bits + 0x7FFFu + ((bits >> 16) & 1u)) >> 16;  // RNE bf16
            ob[q] = (unsigned short)r16;
            float back = __uint_as_float(((unsigned int)ob[q]) << 16);
            nrm += back * back;                   // norm of the bf16-rounded row
        }
        ushort4 o; o.x = ob[0]; o.y = ob[1]; o.z = ob[2]; o.w = ob[3];
        ((ushort4*)dst)[c] = o;
    }
    if (t < 15) {                                 // zero-pad [2500, 2560)
        ushort4 zz; zz.x = zz.y = zz.z = zz.w = 0;
        ((ushort4*)dst)[625 + t] = zz;
    }
#pragma unroll
    for (int off = 32; off; off >>= 1) nrm += __shfl_down(nrm, off);
    __shared__ float red[4];
    int wave = t >> 6;
    if ((t & 63) == 0) red[wave] = nrm;
    __syncthreads();
    if (t == 0) norms[row] = red[0] + red[1] + red[2] + red[3];
}

// ---------------------------------------------------------------------------
// Kernel 2: fused symmetric Gram + exp + reduce, T2-swizzled LDS.
//
// LDS tile [128 rows][64 cols bf16] = 8 chunks of 16B per row.
// Swizzle (involution): LDS slot s of row R holds global chunk s ^ (R&7).
//   - global_load_lds writes linearly (wave base + lane*16B), so lane l
//     (covering row rs+(l>>3), slot l&7) loads PRE-SWIZZLED global chunk
//     (l&7) ^ ((l>>3)&7).
//   - ds_read of row R, chunk c uses slot c ^ (R&7).
// After swizzle, each 16 consecutive lanes cover all 8 slots (32 banks)
// with 2 lanes/slot -> conflict-free (2-way is free per m136).
// ---------------------------------------------------------------------------
__global__ __launch_bounds__(256, 4) void gram_exp_reduce(
    const unsigned short* __restrict__ Z, const float* __restrict__ norms,
    float* __restrict__ accum)
{
    // Bijective XCD-chunk swizzle: 2080 = 8 * 260, each XCD owns a
    // contiguous run of triangle indices (consecutive tiles share A-panels).
    int orig = blockIdx.x;
    int t = (orig & 7) * (NTRI / NXCD) + (orig >> 3);
    // unflatten lower-triangular index: t -> (bi, bj), 0 <= bj <= bi < 64
    int bi = (int)((sqrtf(8.0f * (float)t + 1.0f) - 1.0f) * 0.5f);
    while ((bi + 1) * (bi + 2) / 2 <= t) ++bi;
    while (bi * (bi + 1) / 2 > t) --bi;
    int bj = t - bi * (bi + 1) / 2;

    __shared__ unsigned short As[128 * 64];
    __shared__ unsigned short Bs[128 * 64];
    __shared__ float red[4];

    int tid  = threadIdx.x;
    int wave = tid >> 6, lane = tid & 63;
    int wr = wave >> 1, wc = wave & 1;            // 2x2 wave grid, 64x64 per wave

    const int rowA0 = bi * 128, rowB0 = bj * 128;
    const int lr = lane >> 3;                     // row within 8-row stripe (0..7)
    const int sc = ((lane & 7) ^ lr) * 8;         // pre-swizzled chunk element offset

    // hoisted per-lane global base pointers (advance by +64 per K-step)
    const unsigned short* ga0 = Z + (size_t)(rowA0 + wave * 32 + lr) * LDZ + sc;
    const unsigned short* gb0 = Z + (size_t)(rowB0 + wave * 32 + lr) * LDZ + sc;

    f32x4 zero = {0.f, 0.f, 0.f, 0.f};
    f32x4 acc[4][4];
#pragma unroll
    for (int m = 0; m < 4; ++m)
#pragma unroll
        for (int n = 0; n < 4; ++n) acc[m][n] = zero;

    for (int k0 = 0; k0 < LDZ; k0 += 64) {
        // ---- stage: 4 8-row stripes of A and B per wave, linear LDS dest ----
#pragma unroll
        for (int q = 0; q < 4; ++q) {
            __builtin_amdgcn_global_load_lds(
                (gbl_ushort_t*)(ga0 + (size_t)q * 8 * LDZ + k0),
                (lds_ushort_t*)(As + (wave * 32 + q * 8) * 64), 16, 0, 0);
            __builtin_amdgcn_global_load_lds(
                (gbl_ushort_t*)(gb0 + (size_t)q * 8 * LDZ + k0),
                (lds_ushort_t*)(Bs + (wave * 32 + q * 8) * 64), 16, 0, 0);
        }
        __syncthreads();

        // ---- compute: 2 k-slices x 4x4 MFMA, swizzled ds_read ----
#pragma unroll
        for (int ks = 0; ks < 2; ++ks) {
            int g = lane >> 4;
            int koff = ((ks * 4 + g) ^ (lane & 7)) * 8;   // swizzled slot, row&7 == lane&7
            bf16x8 a[4], b[4];
#pragma unroll
            for (int m = 0; m < 4; ++m)
                a[m] = *(const bf16x8*)&As[(wr * 64 + m * 16 + (lane & 15)) * 64 + koff];
#pragma unroll
            for (int n = 0; n < 4; ++n)
                b[n] = *(const bf16x8*)&Bs[(wc * 64 + n * 16 + (lane & 15)) * 64 + koff];
#pragma unroll
            for (int m = 0; m < 4; ++m)
#pragma unroll
                for (int n = 0; n < 4; ++n)
                    acc[m][n] = __builtin_amdgcn_mfma_f32_16x16x32_bf16(
                        a[m], b[n], acc[m][n], 0, 0, 0);
        }
        __syncthreads();
    }

    // ---- epilogue: d2 -> exp -> weighted block sum -> one atomic ----
    float partial = 0.f;
    int ibl = rowA0 + wr * 64, jbl = rowB0 + wc * 64;
    int r0 = (lane >> 4) * 4, c0 = lane & 15;     // C/D: col=lane&15, row=(lane>>4)*4+r
#pragma unroll
    for (int m = 0; m < 4; ++m) {
        int ibase = ibl + m * 16 + r0;
        float ni[4];
#pragma unroll
        for (int r = 0; r < 4; ++r) ni[r] = norms[ibase + r];
#pragma unroll
        for (int n = 0; n < 4; ++n) {
            int j = jbl + n * 16 + c0;
            float nj = norms[j];
#pragma unroll
            for (int r = 0; r < 4; ++r) {
                int i = ibase + r;
                float d2 = ni[r] + nj - 2.f * acc[m][n][r];
                float s = (i == j) ? 1.f : __expf(-0.5f * fmaxf(d2, 0.f));
                partial += s;
            }
        }
    }
    float w = (bi == bj) ? 1.f : 2.f;             // off-diag tiles count (i,j) and (j,i)
    if ((bi < 32) != (bj < 32)) w = -w;           // mixed x/y quadrant -> -2*xy
    partial *= w;

#pragma unroll
    for (int off = 32; off; off >>= 1) partial += __shfl_down(partial, off);
    if ((tid & 63) == 0) red[wave] = partial;
    __syncthreads();
    if (tid == 0) atomicAdd(accum, red[0] + red[1] + red[2] + red[3]);
}

// ---------------------------------------------------------------------------
// Kernel 3: finalize. result = accum / N^2 + (max(1, avg_step) - 1) * 0.002
// ---------------------------------------------------------------------------
__global__ void finalize(const float* __restrict__ accum,
                         const float* __restrict__ avg_step,
                         float* __restrict__ out)
{
    float pen = (fmaxf(1.f, avg_step[0]) - 1.f) * 0.002f;
    out[0] = accum[0] * (1.f / (4096.f * 4096.f)) + pen;
}

extern "C" void kernel_launch(void* const* d_in, const int* in_sizes, int n_in,
                              void* d_out, int out_size, void* d_ws, size_t ws_size,
                              hipStream_t stream) {
    const float* x        = (const float*)d_in[0];
    const float* y        = (const float*)d_in[1];
    const float* avg_step = (const float*)d_in[2];
    float* out = (float*)d_out;

    unsigned short* Z = (unsigned short*)d_ws;
    size_t zbytes = (size_t)NROWS * LDZ * sizeof(unsigned short);   // ~41.9 MB
    float* norms = (float*)((char*)d_ws + zbytes);
    float* accum = norms + NROWS;

    hipMemsetAsync(accum, 0, sizeof(float), stream);
    convert_rows<<<NROWS, 256, 0, stream>>>(x, y, Z, norms);
    gram_exp_reduce<<<NTRI, 256, 0, stream>>>(Z, norms, accum);
    finalize<<<1, 1, 0, stream>>>(accum, avg_step, out);
}